// Round 11
// baseline (241.382 us; speedup 1.0000x reference)
//
#include <hip/hip_runtime.h>
#include <hip/hip_bf16.h>

typedef __attribute__((ext_vector_type(8))) short short8;      // 8 x bf16 (4 VGPR)
typedef __attribute__((ext_vector_type(4))) float f32x4;       // MFMA acc
typedef __attribute__((ext_vector_type(4))) unsigned int u32x4;

#define NBKT_MAX 392     // max dst buckets (256 nodes each)
#define BNODES 256       // nodes per bucket
#define CAP2 9216        // records per bucket staging (avg 8163, +11 sigma margin)
#define CHUNK 16384      // records per binrank block

static __device__ __forceinline__ unsigned short f2b(float f) {
  unsigned int u = __builtin_bit_cast(unsigned int, f);
  u = (u + 0x7fffu + ((u >> 16) & 1u)) >> 16;   // RNE (cold paths)
  return (unsigned short)u;
}
static __device__ __forceinline__ unsigned short f2b_hw(float f) {
  __hip_bfloat16 h = __float2bfloat16(f);
  return __builtin_bit_cast(unsigned short, h);
}
static __device__ __forceinline__ float b2f(unsigned short h) {
  unsigned int u = ((unsigned int)h) << 16;
  return __builtin_bit_cast(float, u);
}

// ---------------- edge dtype detection ----------------
__global__ void detect_kernel(const int* __restrict__ ew, int* __restrict__ flag) {
  if (threadIdx.x == 0 && blockIdx.x == 0) {
    int z = 0;
#pragma unroll
    for (int i = 1; i < 32; i += 2) z |= ew[i];
    *flag = (z == 0) ? 1 : 0;   // 1 => int64
  }
}

// ---------------- radix-partition pass: bin edges by dst/256 ----------------
// One 16384-record chunk per block, records in registers. Per chunk:
// LDS histogram -> ONE global reservation per bucket -> ranked stores into
// contiguous per-bucket runs (~168B). O(R) work, full-line-dense writes.
__global__ __launch_bounds__(1024) void binrank_kernel(
    const int* __restrict__ ew, int ne, const int* __restrict__ flag,
    int* __restrict__ gcnt, unsigned* __restrict__ stag, int nbkt) {
  __shared__ int hist[NBKT_MAX];
  __shared__ int gbase[NBKT_MAX];
  __shared__ int lcur[NBKT_MAX];
  const int tid = threadIdx.x;
  const int start = blockIdx.x * CHUNK;
  const int is64 = *flag;

  if (tid < nbkt) { hist[tid] = 0; lcur[tid] = 0; }
  __syncthreads();

  unsigned recs[16];
  short bks[16];
#pragma unroll
  for (int k = 0; k < 16; ++k) {
    int e = start + k * 1024 + tid;          // coalesced sub-rounds
    bks[k] = -1;
    if (e < ne) {
      int s, d;
      if (is64) {
        s = __builtin_nontemporal_load(&ew[2 * (size_t)e]);
        d = __builtin_nontemporal_load(&ew[(size_t)2 * ne + 2 * (size_t)e]);
      } else {
        s = __builtin_nontemporal_load(&ew[e]);
        d = __builtin_nontemporal_load(&ew[(size_t)ne + e]);
      }
      bks[k] = (short)((unsigned)d >> 8);
      recs[k] = (((unsigned)d & 255u) << 17) | (unsigned)s;
      atomicAdd(&hist[bks[k]], 1);
    }
  }
  __syncthreads();

  if (tid < nbkt && hist[tid] > 0)
    gbase[tid] = atomicAdd(&gcnt[tid * 16], hist[tid]);   // 64B-padded counters
  __syncthreads();

#pragma unroll
  for (int k = 0; k < 16; ++k) {
    if (bks[k] >= 0) {
      int b = bks[k];
      int r = atomicAdd(&lcur[b], 1);
      int pos = gbase[b] + r;
      if (pos < CAP2) stag[(size_t)b * CAP2 + pos] = recs[k];
    }
  }
}

// ---------------- scan bucket totals -> bucket bases + rowptr[n] -------------
__global__ __launch_bounds__(512) void bscan_kernel(const int* __restrict__ gcnt,
                                                    int* __restrict__ bb,
                                                    int* __restrict__ rowptr,
                                                    int nbkt, int n) {
  __shared__ int sh[512];
  int t = threadIdx.x;
  int v = 0;
  if (t < nbkt) { v = gcnt[t * 16]; v = v < CAP2 ? v : CAP2; }
  sh[t] = v;
  __syncthreads();
  for (int off = 1; off < 512; off <<= 1) {
    int u = (t >= off) ? sh[t - off] : 0;
    __syncthreads();
    sh[t] += u;
    __syncthreads();
  }
  if (t < nbkt) bb[t] = sh[t] - v;   // exclusive base
  if (t == 0) rowptr[n] = sh[511];   // total records
}

// ---------------- per-bucket counting sort -> rowptr/dinv/csr ----------------
// Direct-write variant: csr_src[base+rank] written at rank time. The scatter
// is confined to the bucket's private 32KB region, filled densely by one
// block in a short window -> L2 lines fill and write back once.
__global__ __launch_bounds__(256) void sortwrite_kernel(
    const unsigned* __restrict__ stag, const int* __restrict__ gcnt,
    const int* __restrict__ bb, int* __restrict__ rowptr, float* __restrict__ dinv,
    int* __restrict__ csr_src, int n) {
  __shared__ int cnt[BNODES];
  __shared__ int off_[BNODES];
  const int b = blockIdx.x;
  const int tid = threadIdx.x;
  const int first = b * BNODES;
  int total = gcnt[b * 16]; total = total < CAP2 ? total : CAP2;
  const unsigned* rg = stag + (size_t)b * CAP2;

  cnt[tid] = 0;
  __syncthreads();
  for (int i = tid; i < total; i += 256)
    atomicAdd(&cnt[rg[i] >> 17], 1);
  __syncthreads();

  const int v0 = cnt[tid];
  off_[tid] = v0;
  __syncthreads();
  for (int o = 1; o < 256; o <<= 1) {
    int u = (tid >= o) ? off_[tid - o] : 0;
    __syncthreads();
    off_[tid] += u;
    __syncthreads();
  }
  const int excl = off_[tid] - v0;
  const int base = bb[b];
  const int node = first + tid;
  if (node < n) {
    rowptr[node] = base + excl;
    dinv[node] = rsqrtf((float)(1 + v0));
  }
  __syncthreads();
  cnt[tid] = excl;               // reuse as cursor
  __syncthreads();

  for (int i = tid; i < total; i += 256) {
    unsigned r = rg[i];
    int p = atomicAdd(&cnt[r >> 17], 1);
    csr_src[base + p] = (int)(r & 0x1FFFFu);   // block-local 32KB scatter
  }
}

// ---------------- W_gcn^T cast to bf16: Wt[c][k], c<64, k<512 ----------------
__global__ __launch_bounds__(256) void wt_kernel(const float* __restrict__ Wg,
                                                 unsigned short* __restrict__ Wt) {
  int t = blockIdx.x * 256 + threadIdx.x;   // 32768 total
  int k = t >> 6, c = t & 63;
  Wt[c * 512 + k] = f2b(Wg[t]);             // Wg[k*64 + c]
}

// ------- hs = (bf16(x) @ bf16(W)) * dinv[row]  via MFMA, stored bf16 --------
// x loads nontemporal: streamed once, keep L2 for hbf/stag (agg re-reads them)
__global__ __launch_bounds__(256) void gemm_kernel(const float* __restrict__ x,
                                                   const unsigned short* __restrict__ Wt,
                                                   const float* __restrict__ dinv,
                                                   unsigned short* __restrict__ hbf,
                                                   int nnodes) {
  __shared__ unsigned short Bt[64][40];
  const int tid = threadIdx.x;
  const int lane = tid & 63;
  const int wv = tid >> 6;
  const int l15 = lane & 15;
  const int hi = lane >> 4;
  const int rowbase = blockIdx.x * 128 + wv * 32;

  f32x4 acc[2][4] = {};

  for (int kc = 0; kc < 16; ++kc) {
    const int k0 = kc * 32;
    {
      int c = tid >> 2, seg = tid & 3;
      u32x4 v = *reinterpret_cast<const u32x4*>(Wt + c * 512 + k0 + seg * 8);
      *reinterpret_cast<u32x4*>(&Bt[c][seg * 8]) = v;
    }
    __syncthreads();

    short8 afrag[2];
#pragma unroll
    for (int i = 0; i < 2; ++i) {
      int row = rowbase + i * 16 + l15;
      row = row < nnodes ? row : nnodes - 1;
      const float* p = x + (size_t)row * 512 + k0 + hi * 8;
      f32x4 f0 = __builtin_nontemporal_load(reinterpret_cast<const f32x4*>(p));
      f32x4 f1 = __builtin_nontemporal_load(reinterpret_cast<const f32x4*>(p + 4));
      short8 a;
      a[0] = (short)f2b_hw(f0[0]); a[1] = (short)f2b_hw(f0[1]);
      a[2] = (short)f2b_hw(f0[2]); a[3] = (short)f2b_hw(f0[3]);
      a[4] = (short)f2b_hw(f1[0]); a[5] = (short)f2b_hw(f1[1]);
      a[6] = (short)f2b_hw(f1[2]); a[7] = (short)f2b_hw(f1[3]);
      afrag[i] = a;
    }
#pragma unroll
    for (int j = 0; j < 4; ++j) {
      short8 b = *reinterpret_cast<const short8*>(&Bt[j * 16 + l15][hi * 8]);
      acc[0][j] = __builtin_amdgcn_mfma_f32_16x16x32_bf16(afrag[0], b, acc[0][j], 0, 0, 0);
      acc[1][j] = __builtin_amdgcn_mfma_f32_16x16x32_bf16(afrag[1], b, acc[1][j], 0, 0, 0);
    }
    __syncthreads();
  }

#pragma unroll
  for (int i = 0; i < 2; ++i)
#pragma unroll
    for (int r = 0; r < 4; ++r) {
      int row = rowbase + i * 16 + hi * 4 + r;
      if (row < nnodes) {
        float dv = dinv[row];
#pragma unroll
        for (int j = 0; j < 4; ++j)
          hbf[(size_t)row * 64 + j * 16 + l15] = f2b_hw(acc[i][j][r] * dv);
      }
    }
}

// ------- aggregate: one wave per node, register accumulation, high TLP ------
__global__ __launch_bounds__(256) void agg_kernel(const unsigned short* __restrict__ hbf,
                                                  const int* __restrict__ rowptr,
                                                  const int* __restrict__ csr_src,
                                                  const float* __restrict__ dinv,
                                                  const float* __restrict__ b_gcn,
                                                  const float* __restrict__ W_cls,
                                                  const float* __restrict__ b_cls,
                                                  float* __restrict__ out, int n) {
  const int lane = threadIdx.x & 63;
  const int node = blockIdx.x * 4 + (threadIdx.x >> 6);
  if (node >= n) return;

  const float dn = dinv[node];
  float inner = 0.f;
  const int e0 = rowptr[node], e1 = rowptr[node + 1];
  int e = e0;
  for (; e + 4 <= e1; e += 4) {
    int s0 = csr_src[e], s1 = csr_src[e + 1], s2 = csr_src[e + 2], s3 = csr_src[e + 3];
    float v0 = b2f(hbf[(size_t)s0 * 64 + lane]);
    float v1 = b2f(hbf[(size_t)s1 * 64 + lane]);
    float v2 = b2f(hbf[(size_t)s2 * 64 + lane]);
    float v3 = b2f(hbf[(size_t)s3 * 64 + lane]);
    inner += (v0 + v1) + (v2 + v3);
  }
  for (; e < e1; ++e) {
    int s = csr_src[e];
    inner += b2f(hbf[(size_t)s * 64 + lane]);
  }
  float self = b2f(hbf[(size_t)node * 64 + lane]);
  float h2 = fmaf(dn, inner + self, b_gcn[lane]);
  h2 = h2 > 0.f ? h2 : 0.f;

  float p[7];
#pragma unroll
  for (int c = 0; c < 7; ++c) p[c] = h2 * W_cls[lane * 7 + c];
#pragma unroll
  for (int off = 32; off; off >>= 1) {
#pragma unroll
    for (int c = 0; c < 7; ++c) p[c] += __shfl_xor(p[c], off, 64);
  }
  if (lane == 0) {
    float* o = out + (size_t)node * 7;
#pragma unroll
    for (int c = 0; c < 7; ++c) o[c] = p[c] + b_cls[c];
  }
}

// =================== fallback (r8 pipeline) for odd shapes ===================
__global__ __launch_bounds__(256) void deg8_kernel(const int* __restrict__ ew, int ne,
                                                   const int* __restrict__ flag,
                                                   int* __restrict__ deg8, int n, int ng) {
  int e = blockIdx.x * 256 + threadIdx.x;
  if (e >= ne) return;
  const int gx = blockIdx.x & (ng - 1);
  const int is64 = *flag;
  int d = is64 ? ew[(size_t)2 * ne + 2 * (size_t)e] : ew[(size_t)ne + e];
  atomicAdd(&deg8[(size_t)gx * n + d], 1);
}
__global__ __launch_bounds__(256) void dinvsum_kernel(const int* __restrict__ deg8,
                                                      float* __restrict__ dinv,
                                                      int* __restrict__ edeg,
                                                      int n, int ng) {
  int i = blockIdx.x * 256 + threadIdx.x;
  if (i >= n) return;
  int d = 0;
  for (int g = 0; g < ng; ++g) d += deg8[(size_t)g * n + i];
  edeg[i] = d;
  dinv[i] = rsqrtf((float)(1 + d));
}
__global__ __launch_bounds__(256) void partial_kernel(const int* __restrict__ edeg,
                                                      int* __restrict__ part, int n) {
  int i = blockIdx.x * 256 + threadIdx.x;
  int v = (i < n) ? edeg[i] : 0;
#pragma unroll
  for (int off = 32; off; off >>= 1) v += __shfl_xor(v, off, 64);
  __shared__ int w[4];
  if ((threadIdx.x & 63) == 0) w[threadIdx.x >> 6] = v;
  __syncthreads();
  if (threadIdx.x == 0) part[blockIdx.x] = w[0] + w[1] + w[2] + w[3];
}
__global__ __launch_bounds__(512) void scanpart_kernel(int* __restrict__ part, int nb) {
  __shared__ int sh[512];
  int t = threadIdx.x;
  int v = (t < nb) ? part[t] : 0;
  sh[t] = v;
  __syncthreads();
  for (int off = 1; off < 512; off <<= 1) {
    int u = (t >= off) ? sh[t - off] : 0;
    __syncthreads();
    sh[t] += u;
    __syncthreads();
  }
  if (t < nb) part[t] = sh[t] - v;
}
__global__ __launch_bounds__(256) void fill_kernel(const int* __restrict__ edeg,
                                                   const int* __restrict__ part,
                                                   int* __restrict__ rowptr,
                                                   int* __restrict__ cursor, int n) {
  __shared__ int sh[256];
  int i = blockIdx.x * 256 + threadIdx.x;
  int v = (i < n) ? edeg[i] : 0;
  sh[threadIdx.x] = v;
  __syncthreads();
  for (int off = 1; off < 256; off <<= 1) {
    int t = (threadIdx.x >= off) ? sh[threadIdx.x - off] : 0;
    __syncthreads();
    sh[threadIdx.x] += t;
    __syncthreads();
  }
  int incl = sh[threadIdx.x];
  int excl = incl - v;
  int base = part[blockIdx.x];
  if (i < n) {
    rowptr[i] = base + excl;
    cursor[i] = base + excl;
    if (i == n - 1) rowptr[n] = base + incl;
  }
}
__global__ __launch_bounds__(256) void scatter_kernel(const int* __restrict__ ew, int ne,
                                                      const int* __restrict__ flag,
                                                      int* __restrict__ cursor,
                                                      int* __restrict__ csr_src) {
  int e = blockIdx.x * 256 + threadIdx.x;
  if (e >= ne) return;
  const int is64 = *flag;
  int s, d;
  if (is64) { s = ew[2 * (size_t)e]; d = ew[(size_t)2 * ne + 2 * (size_t)e]; }
  else      { s = ew[e];             d = ew[(size_t)ne + e]; }
  int pos = atomicAdd(&cursor[d], 1);
  csr_src[pos] = s;
}

extern "C" void kernel_launch(void* const* d_in, const int* in_sizes, int n_in,
                              void* d_out, int out_size, void* d_ws, size_t ws_size,
                              hipStream_t stream) {
  const float* x = (const float*)d_in[0];
  const int* ew = (const int*)d_in[1];
  const float* W_gcn = (const float*)d_in[2];
  const float* b_gcn = (const float*)d_in[3];
  const float* W_cls = (const float*)d_in[4];
  const float* b_cls = (const float*)d_in[5];
  float* out = (float*)d_out;

  const int N = in_sizes[0] / 512;              // 100000
  const int NE = in_sizes[1] / 2;               // 3200000
  const int NBKT = (N + BNODES - 1) / BNODES;   // 391

  size_t off = 0;
  auto take = [&](size_t b) { size_t o = off; off += (b + 255) & ~(size_t)255; return o; };
  char* ws = (char*)d_ws;
  int* flag           = (int*)(ws + take(sizeof(int)));
  unsigned short* Wt  = (unsigned short*)(ws + take((size_t)512 * 64 * 2));
  float* dinv         = (float*)(ws + take((size_t)N * 4));
  unsigned short* hbf = (unsigned short*)(ws + take((size_t)N * 64 * 2));
  int* rowptr         = (int*)(ws + take(((size_t)N + 1) * 4));
  int* csr_src        = (int*)(ws + take((size_t)NE * 4));
  const size_t common_off = off;
  // new path
  int* gcnt           = (int*)(ws + take((size_t)NBKT_MAX * 16 * 4));
  int* bb             = (int*)(ws + take((size_t)NBKT_MAX * 4));
  unsigned* stag      = (unsigned*)(ws + take((size_t)NBKT * CAP2 * 4));
  const long avg_per_bkt = (long)NE / (NBKT > 0 ? NBKT : 1);
  const bool newpath = (NBKT <= NBKT_MAX) && (off <= ws_size) &&
                       (avg_per_bkt + 8 * (long)sqrt((double)avg_per_bkt) < CAP2);

  const int nbN = (N + 255) / 256;
  const int nbE = (NE + 255) / 256;

  detect_kernel<<<1, 64, 0, stream>>>(ew, flag);

  if (newpath) {
    const int NBLK_A = (NE + CHUNK - 1) / CHUNK;   // 196
    hipMemsetAsync(gcnt, 0, (size_t)NBKT_MAX * 16 * 4, stream);
    binrank_kernel<<<NBLK_A, 1024, 0, stream>>>(ew, NE, flag, gcnt, stag, NBKT);
    bscan_kernel<<<1, 512, 0, stream>>>(gcnt, bb, rowptr, NBKT, N);
    sortwrite_kernel<<<NBKT, 256, 0, stream>>>(stag, gcnt, bb, rowptr, dinv, csr_src, N);
  } else {
    // fallback: r8 pipeline
    off = common_off;
    int ng = 8;
    int* deg8   = (int*)(ws + take((size_t)ng * N * 4));
    int* edeg   = (int*)(ws + take((size_t)N * 4));
    int* cursor = (int*)(ws + take((size_t)N * 4));
    int* part   = (int*)(ws + take((size_t)512 * 4));
    if (off > ws_size) ng = 1;
    hipMemsetAsync(deg8, 0, (size_t)ng * N * 4, stream);
    deg8_kernel<<<nbE, 256, 0, stream>>>(ew, NE, flag, deg8, N, ng);
    dinvsum_kernel<<<nbN, 256, 0, stream>>>(deg8, dinv, edeg, N, ng);
    partial_kernel<<<nbN, 256, 0, stream>>>(edeg, part, N);
    scanpart_kernel<<<1, 512, 0, stream>>>(part, nbN);
    fill_kernel<<<nbN, 256, 0, stream>>>(edeg, part, rowptr, cursor, N);
    scatter_kernel<<<nbE, 256, 0, stream>>>(ew, NE, flag, cursor, csr_src);
  }

  wt_kernel<<<128, 256, 0, stream>>>(W_gcn, Wt);
  gemm_kernel<<<(N + 127) / 128, 256, 0, stream>>>(x, Wt, dinv, hbf, N);
  agg_kernel<<<(N + 3) / 4, 256, 0, stream>>>(hbf, rowptr, csr_src, dinv,
                                              b_gcn, W_cls, b_cls, out, N);
}

// Round 12
// 215.168 us; speedup vs baseline: 1.1218x; 1.1218x over previous
//
#include <hip/hip_runtime.h>
#include <hip/hip_bf16.h>

typedef __attribute__((ext_vector_type(8))) short short8;      // 8 x bf16 (4 VGPR)
typedef __attribute__((ext_vector_type(4))) float f32x4;       // MFMA acc
typedef __attribute__((ext_vector_type(4))) unsigned int u32x4;

#define NBKT_MAX 392     // max dst buckets (256 nodes each)
#define BNODES 256       // nodes per bucket
#define CAP2 9216        // records per bucket staging (avg 8163, +11 sigma margin)
#define CHUNK 16384      // records per binrank block

static __device__ __forceinline__ unsigned short f2b(float f) {
  unsigned int u = __builtin_bit_cast(unsigned int, f);
  u = (u + 0x7fffu + ((u >> 16) & 1u)) >> 16;   // RNE (cold paths)
  return (unsigned short)u;
}
static __device__ __forceinline__ unsigned short f2b_hw(float f) {
  __hip_bfloat16 h = __float2bfloat16(f);
  return __builtin_bit_cast(unsigned short, h);
}
static __device__ __forceinline__ float b2f(unsigned short h) {
  unsigned int u = ((unsigned int)h) << 16;
  return __builtin_bit_cast(float, u);
}

// ---------------- edge dtype detection ----------------
__global__ void detect_kernel(const int* __restrict__ ew, int* __restrict__ flag) {
  if (threadIdx.x == 0 && blockIdx.x == 0) {
    int z = 0;
#pragma unroll
    for (int i = 1; i < 32; i += 2) z |= ew[i];
    *flag = (z == 0) ? 1 : 0;   // 1 => int64
  }
}

// ---------------- radix-partition pass: bin edges by dst/256 ----------------
// One 16384-record chunk per block, records in registers. Per chunk:
// LDS histogram -> ONE global reservation per bucket -> ranked stores into
// contiguous per-bucket runs (~168B). O(R) work, full-line-dense writes.
__global__ __launch_bounds__(1024) void binrank_kernel(
    const int* __restrict__ ew, int ne, const int* __restrict__ flag,
    int* __restrict__ gcnt, unsigned* __restrict__ stag, int nbkt) {
  __shared__ int hist[NBKT_MAX];
  __shared__ int gbase[NBKT_MAX];
  __shared__ int lcur[NBKT_MAX];
  const int tid = threadIdx.x;
  const int start = blockIdx.x * CHUNK;
  const int is64 = *flag;

  if (tid < nbkt) { hist[tid] = 0; lcur[tid] = 0; }
  __syncthreads();

  unsigned recs[16];
  short bks[16];
#pragma unroll
  for (int k = 0; k < 16; ++k) {
    int e = start + k * 1024 + tid;          // coalesced sub-rounds
    bks[k] = -1;
    if (e < ne) {
      int s, d;
      if (is64) {
        s = __builtin_nontemporal_load(&ew[2 * (size_t)e]);
        d = __builtin_nontemporal_load(&ew[(size_t)2 * ne + 2 * (size_t)e]);
      } else {
        s = __builtin_nontemporal_load(&ew[e]);
        d = __builtin_nontemporal_load(&ew[(size_t)ne + e]);
      }
      bks[k] = (short)((unsigned)d >> 8);
      recs[k] = (((unsigned)d & 255u) << 17) | (unsigned)s;
      atomicAdd(&hist[bks[k]], 1);
    }
  }
  __syncthreads();

  if (tid < nbkt && hist[tid] > 0)
    gbase[tid] = atomicAdd(&gcnt[tid * 16], hist[tid]);   // 64B-padded counters
  __syncthreads();

#pragma unroll
  for (int k = 0; k < 16; ++k) {
    if (bks[k] >= 0) {
      int b = bks[k];
      int r = atomicAdd(&lcur[b], 1);
      int pos = gbase[b] + r;
      if (pos < CAP2) stag[(size_t)b * CAP2 + pos] = recs[k];
    }
  }
}

// ---------------- scan bucket totals -> bucket bases + rowptr[n] -------------
__global__ __launch_bounds__(512) void bscan_kernel(const int* __restrict__ gcnt,
                                                    int* __restrict__ bb,
                                                    int* __restrict__ rowptr,
                                                    int nbkt, int n) {
  __shared__ int sh[512];
  int t = threadIdx.x;
  int v = 0;
  if (t < nbkt) { v = gcnt[t * 16]; v = v < CAP2 ? v : CAP2; }
  sh[t] = v;
  __syncthreads();
  for (int off = 1; off < 512; off <<= 1) {
    int u = (t >= off) ? sh[t - off] : 0;
    __syncthreads();
    sh[t] += u;
    __syncthreads();
  }
  if (t < nbkt) bb[t] = sh[t] - v;   // exclusive base
  if (t == 0) rowptr[n] = sh[511];   // total records
}

// ---------------- per-bucket counting sort -> rowptr/dinv/csr ----------------
// LDS-sort then ONE sequential coalesced write pass: each csr line is written
// once, fully, back-to-back (r11 direct-write variant regressed: 4B dribble
// into L2 lines across the kernel lifetime -> partial-line writebacks).
__global__ __launch_bounds__(256) void sortwrite_kernel(
    const unsigned* __restrict__ stag, const int* __restrict__ gcnt,
    const int* __restrict__ bb, int* __restrict__ rowptr, float* __restrict__ dinv,
    int* __restrict__ csr_src, int n) {
  __shared__ int cnt[BNODES];
  __shared__ int off_[BNODES];
  __shared__ int sorted[CAP2];    // 36 KB
  const int b = blockIdx.x;
  const int tid = threadIdx.x;
  const int first = b * BNODES;
  int total = gcnt[b * 16]; total = total < CAP2 ? total : CAP2;
  const unsigned* rg = stag + (size_t)b * CAP2;

  cnt[tid] = 0;
  __syncthreads();
  for (int i = tid; i < total; i += 256)
    atomicAdd(&cnt[rg[i] >> 17], 1);
  __syncthreads();

  const int v0 = cnt[tid];
  off_[tid] = v0;
  __syncthreads();
  for (int o = 1; o < 256; o <<= 1) {
    int u = (tid >= o) ? off_[tid - o] : 0;
    __syncthreads();
    off_[tid] += u;
    __syncthreads();
  }
  const int excl = off_[tid] - v0;
  const int base = bb[b];
  const int node = first + tid;
  if (node < n) {
    rowptr[node] = base + excl;
    dinv[node] = rsqrtf((float)(1 + v0));
  }
  __syncthreads();
  cnt[tid] = excl;               // reuse as cursor
  __syncthreads();

  for (int i = tid; i < total; i += 256) {
    unsigned r = rg[i];
    int p = atomicAdd(&cnt[r >> 17], 1);
    sorted[p] = (int)(r & 0x1FFFFu);
  }
  __syncthreads();
  for (int i = tid; i < total; i += 256)
    csr_src[base + i] = sorted[i];   // fully coalesced
}

// ---------------- W_gcn^T cast to bf16: Wt[c][k], c<64, k<512 ----------------
__global__ __launch_bounds__(256) void wt_kernel(const float* __restrict__ Wg,
                                                 unsigned short* __restrict__ Wt) {
  int t = blockIdx.x * 256 + threadIdx.x;   // 32768 total
  int k = t >> 6, c = t & 63;
  Wt[c * 512 + k] = f2b(Wg[t]);             // Wg[k*64 + c]
}

// ------- hs = (bf16(x) @ bf16(W)) * dinv[row]  via MFMA, stored bf16 --------
__global__ __launch_bounds__(256) void gemm_kernel(const float* __restrict__ x,
                                                   const unsigned short* __restrict__ Wt,
                                                   const float* __restrict__ dinv,
                                                   unsigned short* __restrict__ hbf,
                                                   int nnodes) {
  __shared__ unsigned short Bt[64][40];
  const int tid = threadIdx.x;
  const int lane = tid & 63;
  const int wv = tid >> 6;
  const int l15 = lane & 15;
  const int hi = lane >> 4;
  const int rowbase = blockIdx.x * 128 + wv * 32;

  f32x4 acc[2][4] = {};

  for (int kc = 0; kc < 16; ++kc) {
    const int k0 = kc * 32;
    {
      int c = tid >> 2, seg = tid & 3;
      u32x4 v = *reinterpret_cast<const u32x4*>(Wt + c * 512 + k0 + seg * 8);
      *reinterpret_cast<u32x4*>(&Bt[c][seg * 8]) = v;
    }
    __syncthreads();

    short8 afrag[2];
#pragma unroll
    for (int i = 0; i < 2; ++i) {
      int row = rowbase + i * 16 + l15;
      row = row < nnodes ? row : nnodes - 1;
      const float* p = x + (size_t)row * 512 + k0 + hi * 8;
      f32x4 f0 = *reinterpret_cast<const f32x4*>(p);
      f32x4 f1 = *reinterpret_cast<const f32x4*>(p + 4);
      short8 a;
      a[0] = (short)f2b_hw(f0[0]); a[1] = (short)f2b_hw(f0[1]);
      a[2] = (short)f2b_hw(f0[2]); a[3] = (short)f2b_hw(f0[3]);
      a[4] = (short)f2b_hw(f1[0]); a[5] = (short)f2b_hw(f1[1]);
      a[6] = (short)f2b_hw(f1[2]); a[7] = (short)f2b_hw(f1[3]);
      afrag[i] = a;
    }
#pragma unroll
    for (int j = 0; j < 4; ++j) {
      short8 b = *reinterpret_cast<const short8*>(&Bt[j * 16 + l15][hi * 8]);
      acc[0][j] = __builtin_amdgcn_mfma_f32_16x16x32_bf16(afrag[0], b, acc[0][j], 0, 0, 0);
      acc[1][j] = __builtin_amdgcn_mfma_f32_16x16x32_bf16(afrag[1], b, acc[1][j], 0, 0, 0);
    }
    __syncthreads();
  }

#pragma unroll
  for (int i = 0; i < 2; ++i)
#pragma unroll
    for (int r = 0; r < 4; ++r) {
      int row = rowbase + i * 16 + hi * 4 + r;
      if (row < nnodes) {
        float dv = dinv[row];
#pragma unroll
        for (int j = 0; j < 4; ++j)
          hbf[(size_t)row * 64 + j * 16 + l15] = f2b_hw(acc[i][j][r] * dv);
      }
    }
}

// ------- aggregate: one wave per node, register accumulation, high TLP ------
__global__ __launch_bounds__(256) void agg_kernel(const unsigned short* __restrict__ hbf,
                                                  const int* __restrict__ rowptr,
                                                  const int* __restrict__ csr_src,
                                                  const float* __restrict__ dinv,
                                                  const float* __restrict__ b_gcn,
                                                  const float* __restrict__ W_cls,
                                                  const float* __restrict__ b_cls,
                                                  float* __restrict__ out, int n) {
  const int lane = threadIdx.x & 63;
  const int node = blockIdx.x * 4 + (threadIdx.x >> 6);
  if (node >= n) return;

  const float dn = dinv[node];
  float inner = 0.f;
  const int e0 = rowptr[node], e1 = rowptr[node + 1];
  int e = e0;
  for (; e + 4 <= e1; e += 4) {
    int s0 = csr_src[e], s1 = csr_src[e + 1], s2 = csr_src[e + 2], s3 = csr_src[e + 3];
    float v0 = b2f(hbf[(size_t)s0 * 64 + lane]);
    float v1 = b2f(hbf[(size_t)s1 * 64 + lane]);
    float v2 = b2f(hbf[(size_t)s2 * 64 + lane]);
    float v3 = b2f(hbf[(size_t)s3 * 64 + lane]);
    inner += (v0 + v1) + (v2 + v3);
  }
  for (; e < e1; ++e) {
    int s = csr_src[e];
    inner += b2f(hbf[(size_t)s * 64 + lane]);
  }
  float self = b2f(hbf[(size_t)node * 64 + lane]);
  float h2 = fmaf(dn, inner + self, b_gcn[lane]);
  h2 = h2 > 0.f ? h2 : 0.f;

  float p[7];
#pragma unroll
  for (int c = 0; c < 7; ++c) p[c] = h2 * W_cls[lane * 7 + c];
#pragma unroll
  for (int off = 32; off; off >>= 1) {
#pragma unroll
    for (int c = 0; c < 7; ++c) p[c] += __shfl_xor(p[c], off, 64);
  }
  if (lane == 0) {
    float* o = out + (size_t)node * 7;
#pragma unroll
    for (int c = 0; c < 7; ++c) o[c] = p[c] + b_cls[c];
  }
}

// =================== fallback (r8 pipeline) for odd shapes ===================
__global__ __launch_bounds__(256) void deg8_kernel(const int* __restrict__ ew, int ne,
                                                   const int* __restrict__ flag,
                                                   int* __restrict__ deg8, int n, int ng) {
  int e = blockIdx.x * 256 + threadIdx.x;
  if (e >= ne) return;
  const int gx = blockIdx.x & (ng - 1);
  const int is64 = *flag;
  int d = is64 ? ew[(size_t)2 * ne + 2 * (size_t)e] : ew[(size_t)ne + e];
  atomicAdd(&deg8[(size_t)gx * n + d], 1);
}
__global__ __launch_bounds__(256) void dinvsum_kernel(const int* __restrict__ deg8,
                                                      float* __restrict__ dinv,
                                                      int* __restrict__ edeg,
                                                      int n, int ng) {
  int i = blockIdx.x * 256 + threadIdx.x;
  if (i >= n) return;
  int d = 0;
  for (int g = 0; g < ng; ++g) d += deg8[(size_t)g * n + i];
  edeg[i] = d;
  dinv[i] = rsqrtf((float)(1 + d));
}
__global__ __launch_bounds__(256) void partial_kernel(const int* __restrict__ edeg,
                                                      int* __restrict__ part, int n) {
  int i = blockIdx.x * 256 + threadIdx.x;
  int v = (i < n) ? edeg[i] : 0;
#pragma unroll
  for (int off = 32; off; off >>= 1) v += __shfl_xor(v, off, 64);
  __shared__ int w[4];
  if ((threadIdx.x & 63) == 0) w[threadIdx.x >> 6] = v;
  __syncthreads();
  if (threadIdx.x == 0) part[blockIdx.x] = w[0] + w[1] + w[2] + w[3];
}
__global__ __launch_bounds__(512) void scanpart_kernel(int* __restrict__ part, int nb) {
  __shared__ int sh[512];
  int t = threadIdx.x;
  int v = (t < nb) ? part[t] : 0;
  sh[t] = v;
  __syncthreads();
  for (int off = 1; off < 512; off <<= 1) {
    int u = (t >= off) ? sh[t - off] : 0;
    __syncthreads();
    sh[t] += u;
    __syncthreads();
  }
  if (t < nb) part[t] = sh[t] - v;
}
__global__ __launch_bounds__(256) void fill_kernel(const int* __restrict__ edeg,
                                                   const int* __restrict__ part,
                                                   int* __restrict__ rowptr,
                                                   int* __restrict__ cursor, int n) {
  __shared__ int sh[256];
  int i = blockIdx.x * 256 + threadIdx.x;
  int v = (i < n) ? edeg[i] : 0;
  sh[threadIdx.x] = v;
  __syncthreads();
  for (int off = 1; off < 256; off <<= 1) {
    int t = (threadIdx.x >= off) ? sh[threadIdx.x - off] : 0;
    __syncthreads();
    sh[threadIdx.x] += t;
    __syncthreads();
  }
  int incl = sh[threadIdx.x];
  int excl = incl - v;
  int base = part[blockIdx.x];
  if (i < n) {
    rowptr[i] = base + excl;
    cursor[i] = base + excl;
    if (i == n - 1) rowptr[n] = base + incl;
  }
}
__global__ __launch_bounds__(256) void scatter_kernel(const int* __restrict__ ew, int ne,
                                                      const int* __restrict__ flag,
                                                      int* __restrict__ cursor,
                                                      int* __restrict__ csr_src) {
  int e = blockIdx.x * 256 + threadIdx.x;
  if (e >= ne) return;
  const int is64 = *flag;
  int s, d;
  if (is64) { s = ew[2 * (size_t)e]; d = ew[(size_t)2 * ne + 2 * (size_t)e]; }
  else      { s = ew[e];             d = ew[(size_t)ne + e]; }
  int pos = atomicAdd(&cursor[d], 1);
  csr_src[pos] = s;
}

extern "C" void kernel_launch(void* const* d_in, const int* in_sizes, int n_in,
                              void* d_out, int out_size, void* d_ws, size_t ws_size,
                              hipStream_t stream) {
  const float* x = (const float*)d_in[0];
  const int* ew = (const int*)d_in[1];
  const float* W_gcn = (const float*)d_in[2];
  const float* b_gcn = (const float*)d_in[3];
  const float* W_cls = (const float*)d_in[4];
  const float* b_cls = (const float*)d_in[5];
  float* out = (float*)d_out;

  const int N = in_sizes[0] / 512;              // 100000
  const int NE = in_sizes[1] / 2;               // 3200000
  const int NBKT = (N + BNODES - 1) / BNODES;   // 391

  size_t off = 0;
  auto take = [&](size_t b) { size_t o = off; off += (b + 255) & ~(size_t)255; return o; };
  char* ws = (char*)d_ws;
  int* flag           = (int*)(ws + take(sizeof(int)));
  unsigned short* Wt  = (unsigned short*)(ws + take((size_t)512 * 64 * 2));
  float* dinv         = (float*)(ws + take((size_t)N * 4));
  unsigned short* hbf = (unsigned short*)(ws + take((size_t)N * 64 * 2));
  int* rowptr         = (int*)(ws + take(((size_t)N + 1) * 4));
  int* csr_src        = (int*)(ws + take((size_t)NE * 4));
  const size_t common_off = off;
  // new path
  int* gcnt           = (int*)(ws + take((size_t)NBKT_MAX * 16 * 4));
  int* bb             = (int*)(ws + take((size_t)NBKT_MAX * 4));
  unsigned* stag      = (unsigned*)(ws + take((size_t)NBKT * CAP2 * 4));
  const long avg_per_bkt = (long)NE / (NBKT > 0 ? NBKT : 1);
  const bool newpath = (NBKT <= NBKT_MAX) && (off <= ws_size) &&
                       (avg_per_bkt + 8 * (long)sqrt((double)avg_per_bkt) < CAP2);

  const int nbN = (N + 255) / 256;
  const int nbE = (NE + 255) / 256;

  detect_kernel<<<1, 64, 0, stream>>>(ew, flag);

  if (newpath) {
    const int NBLK_A = (NE + CHUNK - 1) / CHUNK;   // 196
    hipMemsetAsync(gcnt, 0, (size_t)NBKT_MAX * 16 * 4, stream);
    binrank_kernel<<<NBLK_A, 1024, 0, stream>>>(ew, NE, flag, gcnt, stag, NBKT);
    bscan_kernel<<<1, 512, 0, stream>>>(gcnt, bb, rowptr, NBKT, N);
    sortwrite_kernel<<<NBKT, 256, 0, stream>>>(stag, gcnt, bb, rowptr, dinv, csr_src, N);
  } else {
    // fallback: r8 pipeline
    off = common_off;
    int ng = 8;
    int* deg8   = (int*)(ws + take((size_t)ng * N * 4));
    int* edeg   = (int*)(ws + take((size_t)N * 4));
    int* cursor = (int*)(ws + take((size_t)N * 4));
    int* part   = (int*)(ws + take((size_t)512 * 4));
    if (off > ws_size) ng = 1;
    hipMemsetAsync(deg8, 0, (size_t)ng * N * 4, stream);
    deg8_kernel<<<nbE, 256, 0, stream>>>(ew, NE, flag, deg8, N, ng);
    dinvsum_kernel<<<nbN, 256, 0, stream>>>(deg8, dinv, edeg, N, ng);
    partial_kernel<<<nbN, 256, 0, stream>>>(edeg, part, N);
    scanpart_kernel<<<1, 512, 0, stream>>>(part, nbN);
    fill_kernel<<<nbN, 256, 0, stream>>>(edeg, part, rowptr, cursor, N);
    scatter_kernel<<<nbE, 256, 0, stream>>>(ew, NE, flag, cursor, csr_src);
  }

  wt_kernel<<<128, 256, 0, stream>>>(W_gcn, Wt);
  gemm_kernel<<<(N + 127) / 128, 256, 0, stream>>>(x, Wt, dinv, hbf, N);
  agg_kernel<<<(N + 3) / 4, 256, 0, stream>>>(hbf, rowptr, csr_src, dinv,
                                              b_gcn, W_cls, b_cls, out, N);
}